// Round 5
// baseline (251.897 us; speedup 1.0000x reference)
//
#include <hip/hip_runtime.h>
#include <math.h>

#define BB 16
#define LL 1024
#define DM 6
#define ED 48
#define NST 32
#define DCONVK 16
#define NCLS 4
#define CH 32    // positions per pre-kernel block
#define HALO 15
#define NCF 16   // scan chunks (= waves per scan block)
#define CSF 64   // chunk size = LL/NCF

__device__ __forceinline__ float softplus_f(float x) {
    return fmaxf(x, 0.f) + log1pf(expf(-fabsf(x)));
}
__device__ __forceinline__ float silu_f(float x) {
    return x / (1.f + __expf(-x));
}

// Fused: [MODE0: rmsnorm(x)] / [MODE1: ygT@opw + x residual -> rmsnorm]
//        -> in_proj -> split -> causal dwconv+silu -> x_proj -> softplus(delta)
// Outputs: xT/dT transposed (B,48,L); zT holds silu(z) (B,48,L); Bi/Ci (B,L,32).
template<int MODE>
__global__ __launch_bounds__(256) void pre_kernel(
    const float* __restrict__ hin,     // x (B,L,6): MODE0 input / MODE1 residual
    const float* __restrict__ ygT_in,  // MODE1: (B,48,L)
    const float* __restrict__ opw,     // MODE1: (48,6)
    const float* __restrict__ ipw,     // (6,96)
    const float* __restrict__ nw,      // (6)
    const float* __restrict__ cw,      // (48,16)
    const float* __restrict__ cb,      // (48)
    const float* __restrict__ xpw,     // (48,65)
    const float* __restrict__ dtw,     // (48)
    const float* __restrict__ dtb,     // (48)
    float* __restrict__ xT,            // (B,48,L)
    float* __restrict__ zT,            // (B,48,L)  silu-applied
    float* __restrict__ dT,            // (B,48,L)
    float* __restrict__ Bi,            // (B,L,32)
    float* __restrict__ Ci)            // (B,L,32)
{
    __shared__ float s_ipw[6*96];
    __shared__ float s_nw[6];
    __shared__ float s_cw[48*DCONVK];
    __shared__ float s_cb[48];
    __shared__ float s_xpw[48*65];
    __shared__ float s_dtw[48];
    __shared__ float s_dtb[48];
    __shared__ float s_opw[48*6];
    __shared__ float s_pp[(CH+HALO)*4*6];
    __shared__ float s_u[(CH+HALO)*7];
    __shared__ float s_raw[(CH+HALO)*49];
    __shared__ float s_xsT[48*CH];        // [c][p] channel-major
    __shared__ float s_bc[64*33];         // [col][p] for B/C transpose-out
    __shared__ float s_dlt[CH];

    const int tid = threadIdx.x;
    const int b  = blockIdx.x >> 5;
    const int l0 = (blockIdx.x & 31) * CH;
    const int ROWS = CH + HALO;           // 47

    for (int i = tid; i < 6*96; i += 256) s_ipw[i] = ipw[i];
    if (tid < 6) s_nw[tid] = nw[tid];
    for (int i = tid; i < 48*DCONVK; i += 256) s_cw[i] = cw[i];
    if (tid < 48) s_cb[tid] = cb[tid];
    for (int i = tid; i < 48*65; i += 256) s_xpw[i] = xpw[i];
    if (tid < 48) { s_dtw[tid] = dtw[tid]; s_dtb[tid] = dtb[tid]; }
    if (MODE == 1) for (int i = tid; i < 48*6; i += 256) s_opw[i] = opw[i];
    __syncthreads();

    // ---- phase 0: produce s_u (normalized input rows l0-15 .. l0+CH-1) ----
    if (MODE == 0) {
        if (tid < ROWS) {
            int l = l0 - HALO + tid;
            float u[DM];
            if (l >= 0) {
                float ss = 0.f;
                const float* hp = hin + ((size_t)b*LL + l)*DM;
                #pragma unroll
                for (int d = 0; d < DM; ++d) { u[d] = hp[d]; ss += u[d]*u[d]; }
                float sc = rsqrtf(ss * (1.f/DM) + 1e-5f);
                #pragma unroll
                for (int d = 0; d < DM; ++d) u[d] *= sc * s_nw[d];
            } else {
                #pragma unroll
                for (int d = 0; d < DM; ++d) u[d] = 0.f;
            }
            #pragma unroll
            for (int d = 0; d < DM; ++d) s_u[tid*7+d] = u[d];
        }
        __syncthreads();
    } else {
        // proj0 fused: acc = ygT^T @ opw (split over 4 e-groups), + residual, rmsnorm
        const int g = tid >> 6, t = tid & 63;
        if (t < ROWS) {
            int l = l0 - HALO + t;
            float pacc[DM] = {0,0,0,0,0,0};
            if (l >= 0) {
                for (int e = g*12; e < g*12 + 12; ++e) {
                    float v = ygT_in[((size_t)b*48 + e)*LL + l];
                    #pragma unroll
                    for (int d = 0; d < DM; ++d) pacc[d] += v * s_opw[e*DM+d];
                }
            }
            #pragma unroll
            for (int d = 0; d < DM; ++d) s_pp[(t*4+g)*DM+d] = pacc[d];
        }
        __syncthreads();
        if (tid < ROWS) {
            int l = l0 - HALO + tid;
            float u[DM];
            if (l >= 0) {
                const float* xr = hin + ((size_t)b*LL + l)*DM;
                float ss = 0.f;
                #pragma unroll
                for (int d = 0; d < DM; ++d) {
                    float hv = s_pp[(tid*4+0)*DM+d] + s_pp[(tid*4+1)*DM+d]
                             + s_pp[(tid*4+2)*DM+d] + s_pp[(tid*4+3)*DM+d] + xr[d];
                    u[d] = hv; ss += hv*hv;
                }
                float sc = rsqrtf(ss * (1.f/DM) + 1e-5f);
                #pragma unroll
                for (int d = 0; d < DM; ++d) u[d] *= sc * s_nw[d];
            } else {
                #pragma unroll
                for (int d = 0; d < DM; ++d) u[d] = 0.f;
            }
            #pragma unroll
            for (int d = 0; d < DM; ++d) s_u[tid*7+d] = u[d];
        }
        __syncthreads();
    }

    // ---- phase 1: in_proj (96 cols x ROWS rows); z gets silu applied ----
    for (int i = tid; i < 96*ROWS; i += 256) {
        int j = i / ROWS, t = i - j*ROWS;
        float acc = 0.f;
        #pragma unroll
        for (int d = 0; d < DM; ++d) acc += s_u[t*7+d]*s_ipw[d*96+j];
        if (j < 48) s_raw[t*49+j] = acc;
        else if (t >= HALO)
            zT[((size_t)b*48 + (j-48))*LL + (l0 - HALO + t)] = silu_f(acc);
    }
    __syncthreads();

    // ---- phase 2: depthwise causal conv (K=16) + silu ----
    for (int o = tid; o < 48*CH; o += 256) {
        int c = o >> 5, p = o & 31;
        float acc = s_cb[c];
        #pragma unroll
        for (int k = 0; k < DCONVK; ++k)
            acc += s_raw[(p+k)*49 + c] * s_cw[c*DCONVK + k];
        float v = silu_f(acc);
        s_xsT[c*CH + p] = v;
        xT[((size_t)b*48 + c)*LL + l0 + p] = v;
    }
    __syncthreads();

    // ---- phase 3: x_proj, vectorized 4 positions per lane ----
    for (int i = tid; i < 65*8; i += 256) {
        int j = i >> 3, g = i & 7;
        int col = (j == 64) ? 0 : (j + 1);
        float a0=0.f, a1=0.f, a2=0.f, a3=0.f;
        for (int e = 0; e < 48; ++e) {
            float4 xv = *(const float4*)&s_xsT[e*CH + 4*g];
            float w = s_xpw[e*65 + col];
            a0 = fmaf(xv.x, w, a0); a1 = fmaf(xv.y, w, a1);
            a2 = fmaf(xv.z, w, a2); a3 = fmaf(xv.w, w, a3);
        }
        if (j < 64) {
            s_bc[j*33 + 4*g+0] = a0; s_bc[j*33 + 4*g+1] = a1;
            s_bc[j*33 + 4*g+2] = a2; s_bc[j*33 + 4*g+3] = a3;
        } else {
            s_dlt[4*g+0] = a0; s_dlt[4*g+1] = a1;
            s_dlt[4*g+2] = a2; s_dlt[4*g+3] = a3;
        }
    }
    __syncthreads();

    // ---- phase 3b: write B/C interleaved (coalesced) ----
    for (int o = tid; o < 2*CH*32; o += 256) {
        int which = o >> 10;            // 0:B 1:C
        int l = (o >> 5) & (CH-1), n = o & 31;
        float v = s_bc[(which*32 + n)*33 + l];
        float* dst = which ? Ci : Bi;
        dst[((size_t)b*LL + l0 + l)*32 + n] = v;
    }

    // ---- phase 4: delta = softplus(dlt*dt_w + dt_b), transposed write ----
    for (int o = tid; o < 48*CH; o += 256) {
        int e = o >> 5, p = o & 31;
        float xv = s_dlt[p]*s_dtw[e] + s_dtb[e];
        dT[((size_t)b*48 + e)*LL + l0 + p] = softplus_f(xv);
    }
}

// ---- fully fused selective scan, SINGLE data pass ----
// Block = (b, epair). 1024 threads = 16 waves; wave w owns chunk w (64 steps).
// Phase A: one read of d,x,B,C -> h_local scan, local-y (reduced) into LDS,
//          CP_t = C_t * P_t kept in registers (P = running prod of dA).
// Phase B: carry scan over the 16 chunk (P,h_end) pairs.
// Phase C: corr_t = butterfly(CP_t * carry); y = (y_local + corr) * zsilu.
__global__ __launch_bounds__(1024) void scan_fused(
    const float* __restrict__ dT,
    const float* __restrict__ xT,
    const float* __restrict__ zT,     // silu(z)
    const float* __restrict__ Bi,
    const float* __restrict__ Ci,
    const float* __restrict__ A_log,  // (48,32)
    const float* __restrict__ Dw,     // (48)
    float* __restrict__ ygT)          // (B,48,L)
{
    __shared__ float2 sPH[2][NCF][32];
    __shared__ float  sCa[2][NCF][32];
    __shared__ float  sYL[2][NCF][CSF];

    const int tid = threadIdx.x;
    const int c = tid >> 6;           // wave = chunk
    const int lane = tid & 63;
    const int eh = lane >> 5, n = lane & 31;
    const int b = blockIdx.x / 24;
    const int epair = blockIdx.x % 24;
    const int e = epair*2 + eh;

    const float Ac = -__expf(A_log[e*NST + n]);
    const float Dc = Dw[e];

    const size_t eb = ((size_t)b*48 + e)*LL + c*CSF;
    const float4* dp = (const float4*)(dT + eb);
    const float4* xp = (const float4*)(xT + eb);
    const float*  bp = Bi + ((size_t)b*LL + c*CSF)*32 + n;
    const float*  cp = Ci + ((size_t)b*LL + c*CSF)*32 + n;

    float4 CP[NCF];   // CP_t for this lane's n, 64 steps
    float h = 0.f, P = 1.f;

    // ---- phase A ----
    #pragma unroll
    for (int q = 0; q < CSF/4; ++q) {
        float4 d4 = dp[q], x4 = xp[q];
        float b0 = bp[(4*q+0)*32], b1 = bp[(4*q+1)*32];
        float b2 = bp[(4*q+2)*32], b3 = bp[(4*q+3)*32];
        float c0 = cp[(4*q+0)*32], c1 = cp[(4*q+1)*32];
        float c2 = cp[(4*q+2)*32], c3 = cp[(4*q+3)*32];
        float dA, p0, p1, p2, p3;
        dA = __expf(d4.x*Ac); h = fmaf(dA, h, d4.x*x4.x*b0); P *= dA; CP[q].x = c0*P; p0 = h*c0;
        dA = __expf(d4.y*Ac); h = fmaf(dA, h, d4.y*x4.y*b1); P *= dA; CP[q].y = c1*P; p1 = h*c1;
        dA = __expf(d4.z*Ac); h = fmaf(dA, h, d4.z*x4.z*b2); P *= dA; CP[q].z = c2*P; p2 = h*c2;
        dA = __expf(d4.w*Ac); h = fmaf(dA, h, d4.w*x4.w*b3); P *= dA; CP[q].w = c3*P; p3 = h*c3;
        // packed butterfly reduce over 32 n-lanes (within eh half)
        float q0 = p0 + __shfl_xor(p0, 16);
        float q1 = p1 + __shfl_xor(p1, 16);
        float q2 = p2 + __shfl_xor(p2, 16);
        float q3 = p3 + __shfl_xor(p3, 16);
        float m01 = (n & 16) ? q1 : q0;
        float m23 = (n & 16) ? q3 : q2;
        m01 += __shfl_xor(m01, 8); m23 += __shfl_xor(m23, 8);
        m01 += __shfl_xor(m01, 4); m23 += __shfl_xor(m23, 4);
        m01 += __shfl_xor(m01, 2); m23 += __shfl_xor(m23, 2);
        m01 += __shfl_xor(m01, 1); m23 += __shfl_xor(m23, 1);
        float y1 = __shfl_xor(m01, 16);
        float y3 = __shfl_xor(m23, 16);
        if (n == 0) {
            float4 yl;
            yl.x = m01 + Dc*x4.x;
            yl.y = y1  + Dc*x4.y;
            yl.z = m23 + Dc*x4.z;
            yl.w = y3  + Dc*x4.w;
            *(float4*)&sYL[eh][c][4*q] = yl;
        }
    }
    sPH[eh][c][n] = make_float2(P, h);
    __syncthreads();

    // ---- phase B: carry scan over chunks (wave 0) ----
    if (tid < 64) {
        float2 v[NCF];
        #pragma unroll
        for (int k = 0; k < NCF; ++k) v[k] = sPH[eh][k][n];
        float acc = 0.f;
        #pragma unroll
        for (int k = 0; k < NCF; ++k) {
            sCa[eh][k][n] = acc;
            acc = fmaf(v[k].x, acc, v[k].y);
        }
    }
    __syncthreads();

    // ---- phase C: correction + gate ----
    const float carry = sCa[eh][c][n];
    const float4* zp = (const float4*)(zT + eb);
    float4* yp = (float4*)(ygT + eb);

    #pragma unroll
    for (int q = 0; q < CSF/4; ++q) {
        float r0 = CP[q].x * carry;
        float r1 = CP[q].y * carry;
        float r2 = CP[q].z * carry;
        float r3 = CP[q].w * carry;
        float q0 = r0 + __shfl_xor(r0, 16);
        float q1 = r1 + __shfl_xor(r1, 16);
        float q2 = r2 + __shfl_xor(r2, 16);
        float q3 = r3 + __shfl_xor(r3, 16);
        float m01 = (n & 16) ? q1 : q0;
        float m23 = (n & 16) ? q3 : q2;
        m01 += __shfl_xor(m01, 8); m23 += __shfl_xor(m23, 8);
        m01 += __shfl_xor(m01, 4); m23 += __shfl_xor(m23, 4);
        m01 += __shfl_xor(m01, 2); m23 += __shfl_xor(m23, 2);
        m01 += __shfl_xor(m01, 1); m23 += __shfl_xor(m23, 1);
        float y1 = __shfl_xor(m01, 16);
        float y3 = __shfl_xor(m23, 16);
        if (n == 0) {
            float4 yl = *(const float4*)&sYL[eh][c][4*q];
            float4 zs = zp[q];
            float4 y;
            y.x = (yl.x + m01) * zs.x;
            y.y = (yl.y + y1 ) * zs.y;
            y.z = (yl.z + m23) * zs.z;
            y.w = (yl.w + y3 ) * zs.w;
            yp[q] = y;
        }
    }
}

// feat = relu(h_last @ fc_w + fc_b); logits = feat@cls_w+cls_b; mass = feat@reg_w+reg_b
__global__ __launch_bounds__(1024) void head_kernel(
    const float* __restrict__ ygT,   // layer-1 gated output (B,48,L)
    const float* __restrict__ fcw, const float* __restrict__ fcb,
    const float* __restrict__ clw, const float* __restrict__ clb,
    const float* __restrict__ rgw, const float* __restrict__ rgb,
    float* __restrict__ out)         // 80 floats: (16,4) logits then (16,) mass
{
    __shared__ float s_h[BB*48];
    __shared__ float s_f[BB*48];
    const int tid = threadIdx.x;
    const int b = tid >> 6, j = tid & 63;
    if (j < 48) s_h[b*48+j] = ygT[((size_t)b*48 + j)*LL + (LL-1)];
    __syncthreads();
    if (j < 48) {
        float acc = fcb[j];
        for (int k = 0; k < 48; ++k) acc += s_h[b*48+k]*fcw[k*48+j];
        s_f[b*48+j] = fmaxf(acc, 0.f);
    }
    __syncthreads();
    if (j < NCLS) {
        float acc = clb[j];
        for (int k = 0; k < 48; ++k) acc += s_f[b*48+k]*clw[k*NCLS+j];
        out[b*NCLS + j] = acc;
    }
    if (j == NCLS) {
        float acc = rgb[0];
        for (int k = 0; k < 48; ++k) acc += s_f[b*48+k]*rgw[k];
        out[BB*NCLS + b] = acc;
    }
}

extern "C" void kernel_launch(void* const* d_in, const int* in_sizes, int n_in,
                              void* d_out, int out_size, void* d_ws, size_t ws_size,
                              hipStream_t stream)
{
    const float* x     = (const float*)d_in[0];
    const float* ipw   = (const float*)d_in[1];   // (2,6,96)
    const float* cw    = (const float*)d_in[2];   // (2,48,16)
    const float* cb    = (const float*)d_in[3];   // (2,48)
    const float* xpw   = (const float*)d_in[4];   // (2,48,65)
    const float* dtw   = (const float*)d_in[5];   // (2,1,48)
    const float* dtb   = (const float*)d_in[6];   // (2,48)
    const float* A_log = (const float*)d_in[7];   // (2,48,32)
    const float* Dw    = (const float*)d_in[8];   // (2,48)
    const float* nw    = (const float*)d_in[9];   // (2,6)
    const float* opw   = (const float*)d_in[10];  // (1,48,6)
    const float* fcw   = (const float*)d_in[11];
    const float* fcb   = (const float*)d_in[12];
    const float* clw   = (const float*)d_in[13];
    const float* clb   = (const float*)d_in[14];
    const float* rgw   = (const float*)d_in[15];
    const float* rgb   = (const float*)d_in[16];
    float* out = (float*)d_out;

    float* ws = (float*)d_ws;
    const size_t BL = (size_t)BB*LL;
    float* xT  = ws;
    float* zT  = xT  + BL*48;
    float* dT  = zT  + BL*48;
    float* Bi  = dT  + BL*48;
    float* Ci  = Bi  + BL*32;
    float* ygT = Ci  + BL*32;

    const dim3 preGrid(BB*32), preBlk(256);
    const dim3 scanGrid(BB*24), scanBlk(1024);

    // ---- layer 0 ----
    pre_kernel<0><<<preGrid, preBlk, 0, stream>>>(
        x, nullptr, nullptr, ipw, nw, cw, cb, xpw, dtw, dtb,
        xT, zT, dT, Bi, Ci);
    scan_fused<<<scanGrid, scanBlk, 0, stream>>>(
        dT, xT, zT, Bi, Ci, A_log, Dw, ygT);

    // ---- layer 1 (proj0 + residual + rmsnorm fused into pre) ----
    pre_kernel<1><<<preGrid, preBlk, 0, stream>>>(
        x, ygT, opw, ipw + 6*96, nw + 6, cw + 48*DCONVK, cb + 48,
        xpw + 48*65, dtw + 48, dtb + 48,
        xT, zT, dT, Bi, Ci);
    scan_fused<<<scanGrid, scanBlk, 0, stream>>>(
        dT, xT, zT, Bi, Ci, A_log + 48*NST, Dw + 48, ygT);

    head_kernel<<<dim3(1), dim3(1024), 0, stream>>>(
        ygT, fcw, fcb, clw, clb, rgw, rgb, out);
}

// Round 6
// 200.972 us; speedup vs baseline: 1.2534x; 1.2534x over previous
//
#include <hip/hip_runtime.h>
#include <math.h>

#define BB 16
#define LL 1024
#define DM 6
#define ED 48
#define NST 32
#define DCONVK 16
#define NCLS 4
#define CH 32    // positions per pre-kernel block
#define HALO 15
#define NCF 16   // scan chunks (= waves per scan block)
#define CSF 64   // chunk size = LL/NCF

__device__ __forceinline__ float softplus_f(float x) {
    return fmaxf(x, 0.f) + log1pf(expf(-fabsf(x)));
}
__device__ __forceinline__ float silu_f(float x) {
    return x / (1.f + __expf(-x));
}

// Fused: [MODE0: rmsnorm(x)] / [MODE1: ygT@opw + x residual -> rmsnorm]
//        -> in_proj -> split -> causal dwconv+silu -> x_proj -> softplus(delta)
// Outputs: xT/dT transposed (B,48,L); zT holds silu(z) (B,48,L); Bi/Ci (B,L,32).
template<int MODE>
__global__ __launch_bounds__(256) void pre_kernel(
    const float* __restrict__ hin,     // x (B,L,6): MODE0 input / MODE1 residual
    const float* __restrict__ ygT_in,  // MODE1: (B,48,L)
    const float* __restrict__ opw,     // MODE1: (48,6)
    const float* __restrict__ ipw,     // (6,96)
    const float* __restrict__ nw,      // (6)
    const float* __restrict__ cw,      // (48,16)
    const float* __restrict__ cb,      // (48)
    const float* __restrict__ xpw,     // (48,65)
    const float* __restrict__ dtw,     // (48)
    const float* __restrict__ dtb,     // (48)
    float* __restrict__ xT,            // (B,48,L)
    float* __restrict__ zT,            // (B,48,L)  silu-applied
    float* __restrict__ dT,            // (B,48,L)
    float* __restrict__ Bi,            // (B,L,32)
    float* __restrict__ Ci)            // (B,L,32)
{
    __shared__ float s_ipw[6*96];
    __shared__ float s_nw[6];
    __shared__ float s_cw[48*DCONVK];
    __shared__ float s_cb[48];
    __shared__ float s_xpw[48*65];
    __shared__ float s_dtw[48];
    __shared__ float s_dtb[48];
    __shared__ float s_opw[48*6];
    __shared__ float s_pp[(CH+HALO)*4*6];
    __shared__ float s_u[(CH+HALO)*7];
    __shared__ float s_raw[(CH+HALO)*49];
    __shared__ float s_xsT[48*CH];        // [c][p] channel-major
    __shared__ float s_bc[64*33];         // [col][p] for B/C transpose-out
    __shared__ float s_dlt[CH];

    const int tid = threadIdx.x;
    const int b  = blockIdx.x >> 5;
    const int l0 = (blockIdx.x & 31) * CH;
    const int ROWS = CH + HALO;           // 47

    for (int i = tid; i < 6*96; i += 256) s_ipw[i] = ipw[i];
    if (tid < 6) s_nw[tid] = nw[tid];
    for (int i = tid; i < 48*DCONVK; i += 256) s_cw[i] = cw[i];
    if (tid < 48) s_cb[tid] = cb[tid];
    for (int i = tid; i < 48*65; i += 256) s_xpw[i] = xpw[i];
    if (tid < 48) { s_dtw[tid] = dtw[tid]; s_dtb[tid] = dtb[tid]; }
    if (MODE == 1) for (int i = tid; i < 48*6; i += 256) s_opw[i] = opw[i];
    __syncthreads();

    // ---- phase 0: produce s_u (normalized input rows l0-15 .. l0+CH-1) ----
    if (MODE == 0) {
        if (tid < ROWS) {
            int l = l0 - HALO + tid;
            float u[DM];
            if (l >= 0) {
                float ss = 0.f;
                const float* hp = hin + ((size_t)b*LL + l)*DM;
                #pragma unroll
                for (int d = 0; d < DM; ++d) { u[d] = hp[d]; ss += u[d]*u[d]; }
                float sc = rsqrtf(ss * (1.f/DM) + 1e-5f);
                #pragma unroll
                for (int d = 0; d < DM; ++d) u[d] *= sc * s_nw[d];
            } else {
                #pragma unroll
                for (int d = 0; d < DM; ++d) u[d] = 0.f;
            }
            #pragma unroll
            for (int d = 0; d < DM; ++d) s_u[tid*7+d] = u[d];
        }
        __syncthreads();
    } else {
        // proj0 fused: acc = ygT^T @ opw (split over 4 e-groups), + residual, rmsnorm
        const int g = tid >> 6, t = tid & 63;
        if (t < ROWS) {
            int l = l0 - HALO + t;
            float pacc[DM] = {0,0,0,0,0,0};
            if (l >= 0) {
                for (int e = g*12; e < g*12 + 12; ++e) {
                    float v = ygT_in[((size_t)b*48 + e)*LL + l];
                    #pragma unroll
                    for (int d = 0; d < DM; ++d) pacc[d] += v * s_opw[e*DM+d];
                }
            }
            #pragma unroll
            for (int d = 0; d < DM; ++d) s_pp[(t*4+g)*DM+d] = pacc[d];
        }
        __syncthreads();
        if (tid < ROWS) {
            int l = l0 - HALO + tid;
            float u[DM];
            if (l >= 0) {
                const float* xr = hin + ((size_t)b*LL + l)*DM;
                float ss = 0.f;
                #pragma unroll
                for (int d = 0; d < DM; ++d) {
                    float hv = s_pp[(tid*4+0)*DM+d] + s_pp[(tid*4+1)*DM+d]
                             + s_pp[(tid*4+2)*DM+d] + s_pp[(tid*4+3)*DM+d] + xr[d];
                    u[d] = hv; ss += hv*hv;
                }
                float sc = rsqrtf(ss * (1.f/DM) + 1e-5f);
                #pragma unroll
                for (int d = 0; d < DM; ++d) u[d] *= sc * s_nw[d];
            } else {
                #pragma unroll
                for (int d = 0; d < DM; ++d) u[d] = 0.f;
            }
            #pragma unroll
            for (int d = 0; d < DM; ++d) s_u[tid*7+d] = u[d];
        }
        __syncthreads();
    }

    // ---- phase 1: in_proj (96 cols x ROWS rows); z gets silu applied ----
    for (int i = tid; i < 96*ROWS; i += 256) {
        int j = i / ROWS, t = i - j*ROWS;
        float acc = 0.f;
        #pragma unroll
        for (int d = 0; d < DM; ++d) acc += s_u[t*7+d]*s_ipw[d*96+j];
        if (j < 48) s_raw[t*49+j] = acc;
        else if (t >= HALO)
            zT[((size_t)b*48 + (j-48))*LL + (l0 - HALO + t)] = silu_f(acc);
    }
    __syncthreads();

    // ---- phase 2: depthwise causal conv (K=16) + silu ----
    for (int o = tid; o < 48*CH; o += 256) {
        int c = o >> 5, p = o & 31;
        float acc = s_cb[c];
        #pragma unroll
        for (int k = 0; k < DCONVK; ++k)
            acc += s_raw[(p+k)*49 + c] * s_cw[c*DCONVK + k];
        float v = silu_f(acc);
        s_xsT[c*CH + p] = v;
        xT[((size_t)b*48 + c)*LL + l0 + p] = v;
    }
    __syncthreads();

    // ---- phase 3: x_proj with col-pair register blocking ----
    // thread = (j:32, g:8): computes B col j and C col j (cols j+1, j+33 of xpw)
    // for positions 4g..4g+3. Halves the ds_read_b128 count vs one-col version.
    {
        const int j = tid >> 3, g = tid & 7;
        float a0=0,a1=0,a2=0,a3=0;
        float c0=0,c1=0,c2=0,c3=0;
        for (int e = 0; e < 48; ++e) {
            float4 xv = *(const float4*)&s_xsT[e*CH + 4*g];
            float w1 = s_xpw[e*65 + 1 + j];
            float w2 = s_xpw[e*65 + 33 + j];
            a0 = fmaf(xv.x, w1, a0); a1 = fmaf(xv.y, w1, a1);
            a2 = fmaf(xv.z, w1, a2); a3 = fmaf(xv.w, w1, a3);
            c0 = fmaf(xv.x, w2, c0); c1 = fmaf(xv.y, w2, c1);
            c2 = fmaf(xv.z, w2, c2); c3 = fmaf(xv.w, w2, c3);
        }
        s_bc[j*33 + 4*g+0] = a0; s_bc[j*33 + 4*g+1] = a1;
        s_bc[j*33 + 4*g+2] = a2; s_bc[j*33 + 4*g+3] = a3;
        s_bc[(32+j)*33 + 4*g+0] = c0; s_bc[(32+j)*33 + 4*g+1] = c1;
        s_bc[(32+j)*33 + 4*g+2] = c2; s_bc[(32+j)*33 + 4*g+3] = c3;
    }
    // dlt (xpw col 0), conflict-free: lane p reads bank p
    if (tid < 32) {
        float acc = 0.f;
        for (int e = 0; e < 48; ++e) acc += s_xsT[e*CH + tid]*s_xpw[e*65];
        s_dlt[tid] = acc;
    }
    __syncthreads();

    // ---- phase 3b: write B/C interleaved (coalesced) ----
    for (int o = tid; o < 2*CH*32; o += 256) {
        int which = o >> 10;            // 0:B 1:C
        int l = (o >> 5) & (CH-1), n = o & 31;
        float v = s_bc[(which*32 + n)*33 + l];
        float* dst = which ? Ci : Bi;
        dst[((size_t)b*LL + l0 + l)*32 + n] = v;
    }

    // ---- phase 4: delta = softplus(dlt*dt_w + dt_b), transposed write ----
    for (int o = tid; o < 48*CH; o += 256) {
        int e = o >> 5, p = o & 31;
        float xv = s_dlt[p]*s_dtw[e] + s_dtb[e];
        dT[((size_t)b*48 + e)*LL + l0 + p] = softplus_f(xv);
    }
}

// ---- fully fused selective scan, single h-scan pass ----
// Block = (b, epair). 1024 threads = 16 waves; wave c owns chunk c (64 steps).
// Phase A (lane = eh*32+n): h-local scan over d,x,B,C; local-y into LDS via
//   9-shfl scattered butterfly; S_t prefix (n-independent) into LDS; (P,h_end).
// Phase B: carry scan over 16 chunks; packs (Ac, carry) float2 into LDS.
// Phase C (lane = t): corr_t = sum_n C_t[n]*exp(Ac[n]*S_t)*carry[n];
//   y = (y_local + corr) * silu_z.  No shuffles, no serial chains, coalesced IO.
__global__ __launch_bounds__(1024) void scan_fused(
    const float* __restrict__ dT,
    const float* __restrict__ xT,
    const float* __restrict__ zT,     // silu(z)
    const float* __restrict__ Bi,
    const float* __restrict__ Ci,
    const float* __restrict__ A_log,  // (48,32)
    const float* __restrict__ Dw,     // (48)
    float* __restrict__ ygT)          // (B,48,L)
{
    __shared__ float2 sPH[2][NCF][32];    // (P_chunk, h_end)
    __shared__ float2 sACa[2][NCF][32];   // (Ac, carry)
    __shared__ float  sYL[2][NCF][CSF];   // local y (incl. D*x)
    __shared__ float  sS [2][NCF][CSF];   // delta prefix-sum within chunk

    const int tid = threadIdx.x;
    const int c = tid >> 6;           // wave = chunk
    const int lane = tid & 63;
    const int eh = lane >> 5, n = lane & 31;
    const int b = blockIdx.x / 24;
    const int epair = blockIdx.x % 24;
    const int e = epair*2 + eh;

    const float Ac = -__expf(A_log[e*NST + n]);
    const float Dc = Dw[e];

    const size_t eb = ((size_t)b*48 + e)*LL + c*CSF;
    const float4* dp = (const float4*)(dT + eb);
    const float4* xp = (const float4*)(xT + eb);
    const float*  bp = Bi + ((size_t)b*LL + c*CSF)*32 + n;
    const float*  cp = Ci + ((size_t)b*LL + c*CSF)*32 + n;

    float h = 0.f, S = 0.f;

    // ---- phase A ----
    #pragma unroll
    for (int q = 0; q < CSF/4; ++q) {
        float4 d4 = dp[q], x4 = xp[q];
        float b0 = bp[(4*q+0)*32], b1 = bp[(4*q+1)*32];
        float b2 = bp[(4*q+2)*32], b3 = bp[(4*q+3)*32];
        float c0 = cp[(4*q+0)*32], c1 = cp[(4*q+1)*32];
        float c2 = cp[(4*q+2)*32], c3 = cp[(4*q+3)*32];
        float p0, p1, p2, p3;
        h = fmaf(__expf(d4.x*Ac), h, d4.x*x4.x*b0); p0 = h*c0;
        h = fmaf(__expf(d4.y*Ac), h, d4.y*x4.y*b1); p1 = h*c1;
        h = fmaf(__expf(d4.z*Ac), h, d4.z*x4.z*b2); p2 = h*c2;
        h = fmaf(__expf(d4.w*Ac), h, d4.w*x4.w*b3); p3 = h*c3;
        // delta prefix (n-independent); lane n==0 of each eh stores float4
        float s0 = S + d4.x, s1 = s0 + d4.y, s2 = s1 + d4.z, s3 = s2 + d4.w;
        S = s3;
        if (n == 0) *(float4*)&sS[eh][c][4*q] = make_float4(s0, s1, s2, s3);
        // scattered 9-shfl butterfly: sums land one-per-octet
        float q0 = p0 + __shfl_xor(p0, 16);
        float q1 = p1 + __shfl_xor(p1, 16);
        float q2 = p2 + __shfl_xor(p2, 16);
        float q3 = p3 + __shfl_xor(p3, 16);
        float m01 = (n & 16) ? q1 : q0;
        float m23 = (n & 16) ? q3 : q2;
        m01 += __shfl_xor(m01, 8);
        m23 += __shfl_xor(m23, 8);
        float mm = (n & 8) ? m23 : m01;
        mm += __shfl_xor(mm, 4);
        mm += __shfl_xor(mm, 2);
        mm += __shfl_xor(mm, 1);
        if ((n & 7) == 0) {
            int vidx = ((n >> 4) & 1) | (((n >> 3) & 1) << 1);
            float xv = (vidx & 2) ? ((vidx & 1) ? x4.w : x4.z)
                                  : ((vidx & 1) ? x4.y : x4.x);
            sYL[eh][c][4*q + vidx] = fmaf(Dc, xv, mm);
        }
    }
    sPH[eh][c][n] = make_float2(__expf(Ac*S), h);
    __syncthreads();

    // ---- phase B: carry scan over chunks (wave 0) ----
    if (tid < 64) {
        float2 v[NCF];
        #pragma unroll
        for (int k = 0; k < NCF; ++k) v[k] = sPH[eh][k][n];
        float acc = 0.f;
        #pragma unroll
        for (int k = 0; k < NCF; ++k) {
            sACa[eh][k][n] = make_float2(Ac, acc);
            acc = fmaf(v[k].x, acc, v[k].y);
        }
    }
    __syncthreads();

    // ---- phase C: lane = timestep t; correction + gate, fully parallel ----
    {
        const int t = lane;
        const float4* cpt = (const float4*)(Ci + ((size_t)b*LL + c*CSF + t)*32);
        float4 Cv[8];
        #pragma unroll
        for (int k = 0; k < 8; ++k) Cv[k] = cpt[k];

        #pragma unroll
        for (int eh2 = 0; eh2 < 2; ++eh2) {
            const int e2 = epair*2 + eh2;
            const float St = sS[eh2][c][t];
            const float yl = sYL[eh2][c][t];
            float corr = 0.f;
            #pragma unroll
            for (int k = 0; k < 8; ++k) {
                float4 cv = Cv[k];
                float4 w0 = *(const float4*)&sACa[eh2][c][4*k];     // n=4k,4k+1
                float4 w1 = *(const float4*)&sACa[eh2][c][4*k+2];   // n=4k+2,4k+3
                corr = fmaf(cv.x * __expf(w0.x*St), w0.y, corr);
                corr = fmaf(cv.y * __expf(w0.z*St), w0.w, corr);
                corr = fmaf(cv.z * __expf(w1.x*St), w1.y, corr);
                corr = fmaf(cv.w * __expf(w1.z*St), w1.w, corr);
            }
            const size_t o = ((size_t)b*48 + e2)*LL + c*CSF + t;
            ygT[o] = (yl + corr) * zT[o];
        }
    }
}

// feat = relu(h_last @ fc_w + fc_b); logits = feat@cls_w+cls_b; mass = feat@reg_w+reg_b
__global__ __launch_bounds__(1024) void head_kernel(
    const float* __restrict__ ygT,   // layer-1 gated output (B,48,L)
    const float* __restrict__ fcw, const float* __restrict__ fcb,
    const float* __restrict__ clw, const float* __restrict__ clb,
    const float* __restrict__ rgw, const float* __restrict__ rgb,
    float* __restrict__ out)         // 80 floats: (16,4) logits then (16,) mass
{
    __shared__ float s_h[BB*48];
    __shared__ float s_f[BB*48];
    const int tid = threadIdx.x;
    const int b = tid >> 6, j = tid & 63;
    if (j < 48) s_h[b*48+j] = ygT[((size_t)b*48 + j)*LL + (LL-1)];
    __syncthreads();
    if (j < 48) {
        float acc = fcb[j];
        for (int k = 0; k < 48; ++k) acc += s_h[b*48+k]*fcw[k*48+j];
        s_f[b*48+j] = fmaxf(acc, 0.f);
    }
    __syncthreads();
    if (j < NCLS) {
        float acc = clb[j];
        for (int k = 0; k < 48; ++k) acc += s_f[b*48+k]*clw[k*NCLS+j];
        out[b*NCLS + j] = acc;
    }
    if (j == NCLS) {
        float acc = rgb[0];
        for (int k = 0; k < 48; ++k) acc += s_f[b*48+k]*rgw[k];
        out[BB*NCLS + b] = acc;
    }
}

extern "C" void kernel_launch(void* const* d_in, const int* in_sizes, int n_in,
                              void* d_out, int out_size, void* d_ws, size_t ws_size,
                              hipStream_t stream)
{
    const float* x     = (const float*)d_in[0];
    const float* ipw   = (const float*)d_in[1];   // (2,6,96)
    const float* cw    = (const float*)d_in[2];   // (2,48,16)
    const float* cb    = (const float*)d_in[3];   // (2,48)
    const float* xpw   = (const float*)d_in[4];   // (2,48,65)
    const float* dtw   = (const float*)d_in[5];   // (2,1,48)
    const float* dtb   = (const float*)d_in[6];   // (2,48)
    const float* A_log = (const float*)d_in[7];   // (2,48,32)
    const float* Dw    = (const float*)d_in[8];   // (2,48)
    const float* nw    = (const float*)d_in[9];   // (2,6)
    const float* opw   = (const float*)d_in[10];  // (1,48,6)
    const float* fcw   = (const float*)d_in[11];
    const float* fcb   = (const float*)d_in[12];
    const float* clw   = (const float*)d_in[13];
    const float* clb   = (const float*)d_in[14];
    const float* rgw   = (const float*)d_in[15];
    const float* rgb   = (const float*)d_in[16];
    float* out = (float*)d_out;

    float* ws = (float*)d_ws;
    const size_t BL = (size_t)BB*LL;
    float* xT  = ws;
    float* zT  = xT  + BL*48;
    float* dT  = zT  + BL*48;
    float* Bi  = dT  + BL*48;
    float* Ci  = Bi  + BL*32;
    float* ygT = Ci  + BL*32;

    const dim3 preGrid(BB*32), preBlk(256);
    const dim3 scanGrid(BB*24), scanBlk(1024);

    // ---- layer 0 ----
    pre_kernel<0><<<preGrid, preBlk, 0, stream>>>(
        x, nullptr, nullptr, ipw, nw, cw, cb, xpw, dtw, dtb,
        xT, zT, dT, Bi, Ci);
    scan_fused<<<scanGrid, scanBlk, 0, stream>>>(
        dT, xT, zT, Bi, Ci, A_log, Dw, ygT);

    // ---- layer 1 (proj0 + residual + rmsnorm fused into pre) ----
    pre_kernel<1><<<preGrid, preBlk, 0, stream>>>(
        x, ygT, opw, ipw + 6*96, nw + 6, cw + 48*DCONVK, cb + 48,
        xpw + 48*65, dtw + 48, dtb + 48,
        xT, zT, dT, Bi, Ci);
    scan_fused<<<scanGrid, scanBlk, 0, stream>>>(
        dT, xT, zT, Bi, Ci, A_log + 48*NST, Dw + 48, ygT);

    head_kernel<<<dim3(1), dim3(1024), 0, stream>>>(
        ygT, fcw, fcb, clw, clb, rgw, rgb, out);
}

// Round 7
// 194.401 us; speedup vs baseline: 1.2958x; 1.0338x over previous
//
#include <hip/hip_runtime.h>
#include <math.h>

#define BB 16
#define LL 1024
#define DM 6
#define ED 48
#define NST 32
#define DCONVK 16
#define NCLS 4
#define CH 16    // positions per pre-kernel block
#define HALO 15
#define SNC 16   // scan chunks per block
#define SCS 64   // scan chunk size (SNC*SCS = LL)

__device__ __forceinline__ float softplus_f(float x) {
    return fmaxf(x, 0.f) + log1pf(expf(-fabsf(x)));
}
__device__ __forceinline__ float silu_f(float x) {
    return x / (1.f + __expf(-x));
}

// Fused: [MODE0: rmsnorm(x)] / [MODE1: ygT@opw + x residual -> rmsnorm]
//        -> in_proj -> split -> causal dwconv+silu -> x_proj -> softplus(delta)
// Outputs: xT/dT transposed (B,48,L); zT holds silu(z) (B,48,L); Bi/Ci (B,L,32).
template<int MODE>
__global__ __launch_bounds__(256, 4) void pre_kernel(
    const float* __restrict__ hin,     // x (B,L,6): MODE0 input / MODE1 residual
    const float* __restrict__ ygT_in,  // MODE1: (B,48,L)
    const float* __restrict__ opw,     // MODE1: (48,6)
    const float* __restrict__ ipw,     // (6,96)
    const float* __restrict__ nw,      // (6)
    const float* __restrict__ cw,      // (48,16)
    const float* __restrict__ cb,      // (48)
    const float* __restrict__ xpw,     // (48,65)
    const float* __restrict__ dtw,     // (48)
    const float* __restrict__ dtb,     // (48)
    float* __restrict__ xT,            // (B,48,L)
    float* __restrict__ zT,            // (B,48,L)  silu-applied
    float* __restrict__ dT,            // (B,48,L)
    float* __restrict__ Bi,            // (B,L,32)
    float* __restrict__ Ci)            // (B,L,32)
{
    __shared__ float s_ipw[6*96];
    __shared__ float s_nw[6];
    __shared__ float s_cw[48*DCONVK];
    __shared__ float s_cb[48];
    __shared__ float s_xpw[48*65];
    __shared__ float s_dtw[48];
    __shared__ float s_dtb[48];
    __shared__ float s_opw[48*6];
    __shared__ float s_pp[(CH+HALO)*4*6];
    __shared__ float s_u[(CH+HALO)*7];
    __shared__ float s_raw[(CH+HALO)*49];
    __shared__ float s_xsT[48*CH];        // [c][p] channel-major
    __shared__ float s_bc[64*(CH+1)];     // [col][p] for B/C transpose-out
    __shared__ float s_dlt[CH];

    const int tid = threadIdx.x;
    const int b  = blockIdx.x >> 6;
    const int l0 = (blockIdx.x & 63) * CH;
    const int ROWS = CH + HALO;           // 31

    for (int i = tid; i < 6*96; i += 256) s_ipw[i] = ipw[i];
    if (tid < 6) s_nw[tid] = nw[tid];
    for (int i = tid; i < 48*DCONVK; i += 256) s_cw[i] = cw[i];
    if (tid < 48) s_cb[tid] = cb[tid];
    for (int i = tid; i < 48*65; i += 256) s_xpw[i] = xpw[i];
    if (tid < 48) { s_dtw[tid] = dtw[tid]; s_dtb[tid] = dtb[tid]; }
    if (MODE == 1) for (int i = tid; i < 48*6; i += 256) s_opw[i] = opw[i];
    __syncthreads();

    // ---- phase 0: produce s_u (normalized rows l0-15 .. l0+CH-1) ----
    if (MODE == 0) {
        if (tid < ROWS) {
            int l = l0 - HALO + tid;
            float u[DM];
            if (l >= 0) {
                float ss = 0.f;
                const float* hp = hin + ((size_t)b*LL + l)*DM;
                #pragma unroll
                for (int d = 0; d < DM; ++d) { u[d] = hp[d]; ss += u[d]*u[d]; }
                float sc = rsqrtf(ss * (1.f/DM) + 1e-5f);
                #pragma unroll
                for (int d = 0; d < DM; ++d) u[d] *= sc * s_nw[d];
            } else {
                #pragma unroll
                for (int d = 0; d < DM; ++d) u[d] = 0.f;
            }
            #pragma unroll
            for (int d = 0; d < DM; ++d) s_u[tid*7+d] = u[d];
        }
        __syncthreads();
    } else {
        // proj0 fused: ygT^T @ opw (4 e-groups), + residual, rmsnorm
        const int g = tid >> 6, t = tid & 63;
        if (t < ROWS) {
            int l = l0 - HALO + t;
            float pacc[DM] = {0,0,0,0,0,0};
            if (l >= 0) {
                for (int e = g*12; e < g*12 + 12; ++e) {
                    float v = ygT_in[((size_t)b*48 + e)*LL + l];
                    #pragma unroll
                    for (int d = 0; d < DM; ++d) pacc[d] += v * s_opw[e*DM+d];
                }
            }
            #pragma unroll
            for (int d = 0; d < DM; ++d) s_pp[(t*4+g)*DM+d] = pacc[d];
        }
        __syncthreads();
        if (tid < ROWS) {
            int l = l0 - HALO + tid;
            float u[DM];
            if (l >= 0) {
                const float* xr = hin + ((size_t)b*LL + l)*DM;
                float ss = 0.f;
                #pragma unroll
                for (int d = 0; d < DM; ++d) {
                    float hv = s_pp[(tid*4+0)*DM+d] + s_pp[(tid*4+1)*DM+d]
                             + s_pp[(tid*4+2)*DM+d] + s_pp[(tid*4+3)*DM+d] + xr[d];
                    u[d] = hv; ss += hv*hv;
                }
                float sc = rsqrtf(ss * (1.f/DM) + 1e-5f);
                #pragma unroll
                for (int d = 0; d < DM; ++d) u[d] *= sc * s_nw[d];
            } else {
                #pragma unroll
                for (int d = 0; d < DM; ++d) u[d] = 0.f;
            }
            #pragma unroll
            for (int d = 0; d < DM; ++d) s_u[tid*7+d] = u[d];
        }
        __syncthreads();
    }

    // ---- phase 1: in_proj (96 cols x ROWS rows); z gets silu applied ----
    for (int i = tid; i < 96*ROWS; i += 256) {
        int j = i / ROWS, t = i - j*ROWS;
        float acc = 0.f;
        #pragma unroll
        for (int d = 0; d < DM; ++d) acc += s_u[t*7+d]*s_ipw[d*96+j];
        if (j < 48) s_raw[t*49+j] = acc;
        else if (t >= HALO)
            zT[((size_t)b*48 + (j-48))*LL + (l0 - HALO + t)] = silu_f(acc);
    }
    __syncthreads();

    // ---- phase 2: depthwise causal conv (K=16) + silu ----
    for (int o = tid; o < 48*CH; o += 256) {
        int c = o >> 4, p = o & 15;
        float acc = s_cb[c];
        #pragma unroll
        for (int k = 0; k < DCONVK; ++k)
            acc += s_raw[(p+k)*49 + c] * s_cw[c*DCONVK + k];
        float v = silu_f(acc);
        s_xsT[c*CH + p] = v;
        xT[((size_t)b*48 + c)*LL + l0 + p] = v;
    }
    __syncthreads();

    // ---- phase 3: x_proj. thread = (col j:64, pos-group g:4) ----
    {
        const int j = tid >> 2, g = tid & 3;
        float a0=0,a1=0,a2=0,a3=0;
        for (int e = 0; e < 48; ++e) {
            float4 xv = *(const float4*)&s_xsT[e*CH + 4*g];
            float w = s_xpw[e*65 + 1 + j];
            a0 = fmaf(xv.x, w, a0); a1 = fmaf(xv.y, w, a1);
            a2 = fmaf(xv.z, w, a2); a3 = fmaf(xv.w, w, a3);
        }
        s_bc[j*(CH+1) + 4*g+0] = a0; s_bc[j*(CH+1) + 4*g+1] = a1;
        s_bc[j*(CH+1) + 4*g+2] = a2; s_bc[j*(CH+1) + 4*g+3] = a3;
    }
    if (tid < CH) {
        float acc = 0.f;
        for (int e = 0; e < 48; ++e) acc += s_xsT[e*CH + tid]*s_xpw[e*65];
        s_dlt[tid] = acc;
    }
    __syncthreads();

    // ---- phase 3b: write B/C interleaved (coalesced) ----
    for (int o = tid; o < 2*CH*32; o += 256) {
        int which = o >> 9;             // 0:B 1:C
        int l = (o >> 5) & (CH-1), n = o & 31;
        float v = s_bc[(which*32 + n)*(CH+1) + l];
        float* dst = which ? Ci : Bi;
        dst[((size_t)b*LL + l0 + l)*32 + n] = v;
    }

    // ---- phase 4: delta = softplus(dlt*dt_w + dt_b), transposed write ----
    for (int o = tid; o < 48*CH; o += 256) {
        int e = o >> 4, p = o & 15;
        float xv = s_dlt[p]*s_dtw[e] + s_dtb[e];
        dT[((size_t)b*48 + e)*LL + l0 + p] = softplus_f(xv);
    }
}

// ---- fully fused selective scan, single h-scan pass ----
// Block = (b, e): 512 threads = 8 waves = 16 half-wave units = 16 chunks of 64.
// Unit lane n in [0,32). Grid = B*48 = 768 = exactly 3 blocks/CU.
// Phase A (lane=n): h-local scan over d,x,B,C; local-y into LDS via 9-shfl
//   scattered butterfly; delta-prefix S_t into LDS; (P,h_end) per chunk.
// Phase B: one 32-lane unit scans the 16 chunk carries; stores (Ac,carry).
// Phase C (thread = (chunk,t) x2): corr = sum_n C[n]*exp(Ac[n]*S_t)*carry[n].
__global__ __launch_bounds__(512, 6) void scan_fused(
    const float* __restrict__ dT,
    const float* __restrict__ xT,
    const float* __restrict__ zT,     // silu(z)
    const float* __restrict__ Bi,
    const float* __restrict__ Ci,
    const float* __restrict__ A_log,  // (48,32)
    const float* __restrict__ Dw,     // (48)
    float* __restrict__ ygT)          // (B,48,L)
{
    __shared__ float2 sPH[SNC][32];    // (P_chunk, h_end)
    __shared__ float2 sACa[SNC][32];   // (Ac, carry)
    __shared__ float  sYL[SNC][SCS];   // local y (incl. D*x)
    __shared__ float  sS [SNC][SCS];   // delta prefix-sum within chunk

    const int tid = threadIdx.x;
    const int lane = tid & 63;
    const int ch = lane >> 5, n = lane & 31;
    const int c = (tid >> 6)*2 + ch;   // chunk in [0,16)
    const int b = blockIdx.x / 48;
    const int e = blockIdx.x % 48;

    const float Ac = -__expf(A_log[e*NST + n]);
    const float Dc = Dw[e];

    const size_t eb = ((size_t)b*48 + e)*LL + c*SCS;
    const float4* dp = (const float4*)(dT + eb);
    const float4* xp = (const float4*)(xT + eb);
    const float*  bp = Bi + ((size_t)b*LL + c*SCS)*32 + n;
    const float*  cp = Ci + ((size_t)b*LL + c*SCS)*32 + n;

    float h = 0.f, S = 0.f;

    // ---- phase A ----
    #pragma unroll
    for (int q = 0; q < SCS/4; ++q) {
        float4 d4 = dp[q], x4 = xp[q];
        float b0 = bp[(4*q+0)*32], b1 = bp[(4*q+1)*32];
        float b2 = bp[(4*q+2)*32], b3 = bp[(4*q+3)*32];
        float c0 = cp[(4*q+0)*32], c1 = cp[(4*q+1)*32];
        float c2 = cp[(4*q+2)*32], c3 = cp[(4*q+3)*32];
        float p0, p1, p2, p3;
        h = fmaf(__expf(d4.x*Ac), h, d4.x*x4.x*b0); p0 = h*c0;
        h = fmaf(__expf(d4.y*Ac), h, d4.y*x4.y*b1); p1 = h*c1;
        h = fmaf(__expf(d4.z*Ac), h, d4.z*x4.z*b2); p2 = h*c2;
        h = fmaf(__expf(d4.w*Ac), h, d4.w*x4.w*b3); p3 = h*c3;
        // delta prefix (n-independent); lane n==0 of each unit stores float4
        float s0 = S + d4.x, s1 = s0 + d4.y, s2 = s1 + d4.z, s3 = s2 + d4.w;
        S = s3;
        if (n == 0) *(float4*)&sS[c][4*q] = make_float4(s0, s1, s2, s3);
        // scattered 9-shfl butterfly: 4 sums land one-per-octet
        float q0 = p0 + __shfl_xor(p0, 16);
        float q1 = p1 + __shfl_xor(p1, 16);
        float q2 = p2 + __shfl_xor(p2, 16);
        float q3 = p3 + __shfl_xor(p3, 16);
        float m01 = (n & 16) ? q1 : q0;
        float m23 = (n & 16) ? q3 : q2;
        m01 += __shfl_xor(m01, 8);
        m23 += __shfl_xor(m23, 8);
        float mm = (n & 8) ? m23 : m01;
        mm += __shfl_xor(mm, 4);
        mm += __shfl_xor(mm, 2);
        mm += __shfl_xor(mm, 1);
        if ((n & 7) == 0) {
            int vidx = ((n >> 4) & 1) | (((n >> 3) & 1) << 1);
            float xv = (vidx & 2) ? ((vidx & 1) ? x4.w : x4.z)
                                  : ((vidx & 1) ? x4.y : x4.x);
            sYL[c][4*q + vidx] = fmaf(Dc, xv, mm);
        }
    }
    sPH[c][n] = make_float2(__expf(Ac*S), h);
    __syncthreads();

    // ---- phase B: carry scan over 16 chunks (one 32-lane unit) ----
    if (tid < 32) {
        float2 v[SNC];
        #pragma unroll
        for (int k = 0; k < SNC; ++k) v[k] = sPH[k][tid];
        float acc = 0.f;
        #pragma unroll
        for (int k = 0; k < SNC; ++k) {
            sACa[k][tid] = make_float2(Ac, acc);
            acc = fmaf(v[k].x, acc, v[k].y);
        }
    }
    __syncthreads();

    // ---- phase C: thread = (chunk, t), 2 rounds; correction + gate ----
    #pragma unroll
    for (int r = 0; r < 2; ++r) {
        const int c2 = (tid >> 6) + 8*r;
        const int t = lane;
        const float St = sS[c2][t];
        const float yl = sYL[c2][t];
        const float4* cpt = (const float4*)(Ci + ((size_t)b*LL + c2*SCS + t)*32);
        float corr = 0.f;
        #pragma unroll
        for (int k = 0; k < 8; ++k) {
            float4 cv = cpt[k];
            float4 w0 = *(const float4*)&sACa[c2][4*k];     // n=4k,4k+1
            float4 w1 = *(const float4*)&sACa[c2][4*k+2];   // n=4k+2,4k+3
            corr = fmaf(cv.x * __expf(w0.x*St), w0.y, corr);
            corr = fmaf(cv.y * __expf(w0.z*St), w0.w, corr);
            corr = fmaf(cv.z * __expf(w1.x*St), w1.y, corr);
            corr = fmaf(cv.w * __expf(w1.z*St), w1.w, corr);
        }
        const size_t o = ((size_t)b*48 + e)*LL + c2*SCS + t;
        ygT[o] = (yl + corr) * zT[o];
    }
}

// feat = relu(h_last @ fc_w + fc_b); logits = feat@cls_w+cls_b; mass = feat@reg_w+reg_b
__global__ __launch_bounds__(1024) void head_kernel(
    const float* __restrict__ ygT,   // layer-1 gated output (B,48,L)
    const float* __restrict__ fcw, const float* __restrict__ fcb,
    const float* __restrict__ clw, const float* __restrict__ clb,
    const float* __restrict__ rgw, const float* __restrict__ rgb,
    float* __restrict__ out)         // 80 floats: (16,4) logits then (16,) mass
{
    __shared__ float s_h[BB*48];
    __shared__ float s_f[BB*48];
    const int tid = threadIdx.x;
    const int b = tid >> 6, j = tid & 63;
    if (j < 48) s_h[b*48+j] = ygT[((size_t)b*48 + j)*LL + (LL-1)];
    __syncthreads();
    if (j < 48) {
        float acc = fcb[j];
        for (int k = 0; k < 48; ++k) acc += s_h[b*48+k]*fcw[k*48+j];
        s_f[b*48+j] = fmaxf(acc, 0.f);
    }
    __syncthreads();
    if (j < NCLS) {
        float acc = clb[j];
        for (int k = 0; k < 48; ++k) acc += s_f[b*48+k]*clw[k*NCLS+j];
        out[b*NCLS + j] = acc;
    }
    if (j == NCLS) {
        float acc = rgb[0];
        for (int k = 0; k < 48; ++k) acc += s_f[b*48+k]*rgw[k];
        out[BB*NCLS + b] = acc;
    }
}

extern "C" void kernel_launch(void* const* d_in, const int* in_sizes, int n_in,
                              void* d_out, int out_size, void* d_ws, size_t ws_size,
                              hipStream_t stream)
{
    const float* x     = (const float*)d_in[0];
    const float* ipw   = (const float*)d_in[1];   // (2,6,96)
    const float* cw    = (const float*)d_in[2];   // (2,48,16)
    const float* cb    = (const float*)d_in[3];   // (2,48)
    const float* xpw   = (const float*)d_in[4];   // (2,48,65)
    const float* dtw   = (const float*)d_in[5];   // (2,1,48)
    const float* dtb   = (const float*)d_in[6];   // (2,48)
    const float* A_log = (const float*)d_in[7];   // (2,48,32)
    const float* Dw    = (const float*)d_in[8];   // (2,48)
    const float* nw    = (const float*)d_in[9];   // (2,6)
    const float* opw   = (const float*)d_in[10];  // (1,48,6)
    const float* fcw   = (const float*)d_in[11];
    const float* fcb   = (const float*)d_in[12];
    const float* clw   = (const float*)d_in[13];
    const float* clb   = (const float*)d_in[14];
    const float* rgw   = (const float*)d_in[15];
    const float* rgb   = (const float*)d_in[16];
    float* out = (float*)d_out;

    float* ws = (float*)d_ws;
    const size_t BL = (size_t)BB*LL;
    float* xT  = ws;
    float* zT  = xT  + BL*48;
    float* dT  = zT  + BL*48;
    float* Bi  = dT  + BL*48;
    float* Ci  = Bi  + BL*32;
    float* ygT = Ci  + BL*32;

    const dim3 preGrid(BB*64), preBlk(256);
    const dim3 scanGrid(BB*48), scanBlk(512);

    // ---- layer 0 ----
    pre_kernel<0><<<preGrid, preBlk, 0, stream>>>(
        x, nullptr, nullptr, ipw, nw, cw, cb, xpw, dtw, dtb,
        xT, zT, dT, Bi, Ci);
    scan_fused<<<scanGrid, scanBlk, 0, stream>>>(
        dT, xT, zT, Bi, Ci, A_log, Dw, ygT);

    // ---- layer 1 (proj0 + residual + rmsnorm fused into pre) ----
    pre_kernel<1><<<preGrid, preBlk, 0, stream>>>(
        x, ygT, opw, ipw + 6*96, nw + 6, cw + 48*DCONVK, cb + 48,
        xpw + 48*65, dtw + 48, dtb + 48,
        xT, zT, dT, Bi, Ci);
    scan_fused<<<scanGrid, scanBlk, 0, stream>>>(
        dT, xT, zT, Bi, Ci, A_log + 48*NST, Dw + 48, ygT);

    head_kernel<<<dim3(1), dim3(1024), 0, stream>>>(
        ygT, fcw, fcb, clw, clb, rgw, rgb, out);
}